// Round 22
// baseline (128.520 us; speedup 1.0000x reference)
//
#include <hip/hip_runtime.h>
#include <cmath>

// GraphSAGE forward for MI355X (gfx950).
// R22: R21/R19 base (best, 128.0us) + bijective XCD-aligned block swizzle on
//      fused_gather_gemm / gemm40_softmax: the build writes cnt/col for node
//      partition g from XCD g only; aligning consumer blocks to the same XCD
//      makes the per-wave serial head (cnt -> col bin -> out row) local-L2.

typedef _Float16 half_t;
typedef half_t half2_t __attribute__((ext_vector_type(2)));
typedef half_t half4_t __attribute__((ext_vector_type(4)));
typedef half_t half8_t __attribute__((ext_vector_type(8)));

#if defined(__has_builtin)
# if __has_builtin(__builtin_amdgcn_fdot2)
#  define FDOT2(a, b, c) __builtin_amdgcn_fdot2((a), (b), (c), false)
# endif
#endif
#ifndef FDOT2
# define FDOT2(a, b, c) fmaf((float)(a)[0], (float)(b)[0], fmaf((float)(a)[1], (float)(b)[1], (c)))
#endif

#define NXCD 8
#define CAP  64          // bin capacity == wave width
#define EDGE_BLOCKS 2048 // 256 blocks/group

// Bijective XCD swizzle (m204 form): round-robin HW mapping (xcd = orig%8)
// -> XCD xcd handles a CONTIGUOUS logical block range.
__device__ __forceinline__ int xcd_swz(int orig, int nblocks) {
    int xcd = orig & 7;
    int idx = orig >> 3;
    int q = nblocks >> 3, r = nblocks & 7;
    return (xcd < r ? xcd * (q + 1) : r * (q + 1) + (xcd - r) * q) + idx;
}

// --- Fused: binned CSR build + wconv (edge blocks) || H1 GEMM (trailing blocks) ---
// Wt chunk-major: Wt[m*4096 + i*512 + c*8 + j] = Wsrc[(i*8+j)*KOUT + c].
__global__ __launch_bounds__(256) void build_h1(
    const int* __restrict__ src, const int* __restrict__ dst,
    const float* __restrict__ x, const float* __restrict__ W1,
    const float* __restrict__ b1,
    const float* __restrict__ W2, const float* __restrict__ Wp1,
    const float* __restrict__ Wp2,
    half_t* __restrict__ Wt, int* __restrict__ cnt,
    unsigned short* __restrict__ col, half_t* __restrict__ Hh,
    int E, int N)
{
    const int tid = threadIdx.x;

    if (blockIdx.x < EDGE_BLOCKS) {
        int gid = blockIdx.x * 256 + tid;
        if (gid < 3 * 4096) {       // wconv -> chunk-major fp16
            int which = gid >> 12, r = gid & 4095;
            int i = r >> 9, c = (r >> 3) & 63, j = r & 7;
            int k = i * 8 + j;
            float v;
            if      (which == 0) v = W2[k * 64 + c];
            else if (which == 1) v = Wp1[k * 64 + c];
            else                 v = (c < 40) ? Wp2[k * 40 + c] : 0.f;
            Wt[gid] = (half_t)v;
        }

        const int g     = blockIdx.x & (NXCD - 1);
        const int bpg   = blockIdx.x >> 3;
        const int nbpg  = EDGE_BLOCKS >> 3;
        const int chunk = (N + NXCD - 1) / NXCD;
        const int lo = g * chunk;
        const int hi = min(N, lo + chunk);
        const int4* src4 = (const int4*)src;
        const int4* dst4 = (const int4*)dst;
        const int quads = E >> 2;
        for (int q = bpg * 256 + tid; q < quads; q += nbpg * 256) {
            int4 s4 = src4[q];
            bool any = (s4.x >= lo && s4.x < hi) || (s4.y >= lo && s4.y < hi) ||
                       (s4.z >= lo && s4.z < hi) || (s4.w >= lo && s4.w < hi);
            if (!any) continue;
            int4 d4 = dst4[q];
            if (s4.x >= lo && s4.x < hi) {
                int pos = atomicAdd(&cnt[s4.x], 1);
                if (pos < CAP) col[(size_t)s4.x * CAP + pos] = (unsigned short)d4.x;
            }
            if (s4.y >= lo && s4.y < hi) {
                int pos = atomicAdd(&cnt[s4.y], 1);
                if (pos < CAP) col[(size_t)s4.y * CAP + pos] = (unsigned short)d4.y;
            }
            if (s4.z >= lo && s4.z < hi) {
                int pos = atomicAdd(&cnt[s4.z], 1);
                if (pos < CAP) col[(size_t)s4.z * CAP + pos] = (unsigned short)d4.z;
            }
            if (s4.w >= lo && s4.w < hi) {
                int pos = atomicAdd(&cnt[s4.w], 1);
                if (pos < CAP) col[(size_t)s4.w * CAP + pos] = (unsigned short)d4.w;
            }
        }
        if (blockIdx.x == 0 && tid < (E & 3)) {
            int e = (E & ~3) + tid;
            int s = src[e];
            int pos = atomicAdd(&cnt[s], 1);
            if (pos < CAP) col[(size_t)s * CAP + pos] = (unsigned short)dst[e];
        }
    } else {
        // H1 GEMM: 16 rows/block, chunked W1 (low VGPR), raw fp32 W1 reads.
        __shared__ half_t xs[16][64];
        const int lane = tid & 63;
        const int wid  = tid >> 6;
        const int row0 = (blockIdx.x - EDGE_BLOCKS) * 16;

        for (int i = tid; i < 16 * 64; i += 256) {
            int rr = row0 + (i >> 6);
            float v = (rr < N) ? x[(size_t)row0 * 64 + i] : 0.f;
            xs[i >> 6][i & 63] = (half_t)v;
        }
        const float bias = b1[lane];
        __syncthreads();

        float acc[4] = {bias, bias, bias, bias};
#pragma unroll 1
        for (int c = 0; c < 4; ++c) {
            half2_t wr[8];
#pragma unroll
            for (int j = 0; j < 8; ++j) {
                float a0 = W1[(c * 16 + 2 * j + 0) * 64 + lane];
                float a1 = W1[(c * 16 + 2 * j + 1) * 64 + lane];
                half2_t h; h[0] = (half_t)a0; h[1] = (half_t)a1;
                wr[j] = h;
            }
#pragma unroll
            for (int r = 0; r < 4; ++r) {
                const half2_t* xp = (const half2_t*)&xs[wid * 4 + r][c * 16];
#pragma unroll
                for (int j = 0; j < 8; ++j) acc[r] = FDOT2(xp[j], wr[j], acc[r]);
            }
        }
#pragma unroll
        for (int r = 0; r < 4; ++r) {
            int grow = row0 + wid * 4 + r;
            if (grow < N) Hh[(size_t)grow * 64 + lane] = (half_t)acc[r];
        }
    }
}

// Half4 gather with pre-scaled byte offsets.
__device__ __forceinline__ void gather_node(const char* __restrict__ Hbytes,
                                            const unsigned short* __restrict__ cbase,
                                            int deg, int grp, int suboff, float* f) {
    const int myo = ((int)cbase[threadIdx.x & 63]) << 7;   // row byte offset
    f[0] = f[1] = f[2] = f[3] = 0.f;
    const int full = deg & ~15;
    int e = 0;
    for (; e < full; e += 16) {
        half4_t hacc; hacc[0] = (half_t)0.f; hacc[1] = (half_t)0.f;
        hacc[2] = (half_t)0.f; hacc[3] = (half_t)0.f;
#pragma unroll
        for (int i = 0; i < 4; ++i) {
            int off = __shfl(myo, e + 4 * i + grp);
            hacc += *(const half4_t*)(Hbytes + off + suboff);
        }
        f[0] += (float)hacc[0]; f[1] += (float)hacc[1];
        f[2] += (float)hacc[2]; f[3] += (float)hacc[3];
    }
    if (e < deg) {                                         // exec-masked tail
        half4_t hacc; hacc[0] = (half_t)0.f; hacc[1] = (half_t)0.f;
        hacc[2] = (half_t)0.f; hacc[3] = (half_t)0.f;
#pragma unroll
        for (int i = 0; i < 4; ++i) {
            int idx = e + 4 * i + grp;
            int off = __shfl(myo, idx & 63);
            if (idx < deg) hacc += *(const half4_t*)(Hbytes + off + suboff);
        }
        f[0] += (float)hacc[0]; f[1] += (float)hacc[1];
        f[2] += (float)hacc[2]; f[3] += (float)hacc[3];
    }
#pragma unroll
    for (int k = 0; k < 4; ++k) {
        f[k] += __shfl_xor(f[k], 16);
        f[k] += __shfl_xor(f[k], 32);
    }
}

// Linear LDS copy of a chunk-major 4096-half W image (uint4, coalesced).
__device__ __forceinline__ void stage_w(const half_t* __restrict__ Wt,
                                        half_t* __restrict__ wlds, int tid, int nthr) {
    const uint4* ws = (const uint4*)Wt;
    uint4* wd = (uint4*)wlds;
    for (int i = tid; i < 512; i += nthr) wd[i] = ws[i];
}

// b128-clean dot: acc pair += xrow . W(col=lane); W chunk-major in LDS.
__device__ __forceinline__ void dot64_b128(const half_t* __restrict__ xrow,
                                           const half_t* __restrict__ wlds,
                                           int lane, float& a0, float& a1) {
    const half8_t* wl8 = (const half8_t*)wlds;     // [8][64] half8
    const half8_t* xp8 = (const half8_t*)xrow;
#pragma unroll
    for (int i = 0; i < 8; ++i) {
        half8_t wv = wl8[i * 64 + lane];           // contiguous b128
        half8_t xv = xp8[i];                       // broadcast b128
        const half2_t* w2 = (const half2_t*)&wv;
        const half2_t* x2 = (const half2_t*)&xv;
        a0 = FDOT2(x2[0], w2[0], a0);
        a1 = FDOT2(x2[1], w2[1], a1);
        a0 = FDOT2(x2[2], w2[2], a0);
        a1 = FDOT2(x2[3], w2[3], a1);
    }
}

// Fused: Y[node] = relu(mean_gather(H)[node]) @ W + b. 512 thr = 8 waves = 8 nodes.
// XCD-aligned: logical block range per XCD matches the build's node partition.
__global__ __launch_bounds__(512) void fused_gather_gemm(
    const half_t* __restrict__ H, const int* __restrict__ cnt,
    const unsigned short* __restrict__ colb, const half_t* __restrict__ Wt,
    const float* __restrict__ b, half_t* __restrict__ Y, int N, int nblocks)
{
    __shared__ __align__(16) half_t wlds[4096];
    __shared__ __align__(16) half_t xrow[8][64];
    const int tid  = threadIdx.x;
    const int w    = tid >> 6;
    const int lane = tid & 63;
    const int grp  = lane >> 4;
    const int sub  = lane & 15;

    stage_w(Wt, wlds, tid, 512);
    __syncthreads();                                   // only barrier

    const int node = xcd_swz(blockIdx.x, nblocks) * 8 + w;
    if (node >= N) return;

    const int deg = cnt[node];
    float f[4];
    gather_node((const char*)H, colb + (size_t)node * CAP, deg, grp, sub * 8, f);
    if (grp == 0) {                                    // lanes 0-15 write 8B each
        float inv = (deg > 0) ? 1.f / (float)deg : 0.f;
        half4_t o;
        o[0] = (half_t)fmaxf(f[0] * inv, 0.f);
        o[1] = (half_t)fmaxf(f[1] * inv, 0.f);
        o[2] = (half_t)fmaxf(f[2] * inv, 0.f);
        o[3] = (half_t)fmaxf(f[3] * inv, 0.f);
        ((half4_t*)xrow[w])[sub] = o;                  // wave-private
    }

    float a0 = b[lane], a1 = 0.f;
    dot64_b128(xrow[w], wlds, lane, a0, a1);
    Y[(size_t)node * 64 + lane] = (half_t)(a0 + a1);
}

// out[row] = log_softmax( H3[row] @ Wp2 + bp2 ). Dense 16 rows/block; b128 reads.
__global__ __launch_bounds__(256) void gemm40_softmax(const half_t* __restrict__ H3,
                                                      const half_t* __restrict__ Wt2,
                                                      const float* __restrict__ bp2,
                                                      float* __restrict__ out, int n,
                                                      int nblocks) {
    __shared__ __align__(16) half_t xs[16][64];
    __shared__ __align__(16) half_t wlds[4096];
    const int tid  = threadIdx.x;
    const int lane = tid & 63;
    const int wid  = tid >> 6;
    const int row0 = xcd_swz(blockIdx.x, nblocks) * 16;

    stage_w(Wt2, wlds, tid, 256);
    {
        const half2_t* X2 = (const half2_t*)H3;
        half2_t z; z[0] = (half_t)0.f; z[1] = (half_t)0.f;
        for (int i = tid; i < 16 * 32; i += 256) {
            int rr = row0 + (i >> 5);
            ((half2_t*)xs)[i] = (rr < n) ? X2[(size_t)row0 * 32 + i] : z;
        }
    }
    const float bias2 = (lane < 40) ? bp2[lane] : 0.f;
    __syncthreads();

    float a0[4] = {bias2, bias2, bias2, bias2};
    float a1[4] = {0.f, 0.f, 0.f, 0.f};
    const half8_t* wl8 = (const half8_t*)wlds;
#pragma unroll
    for (int i = 0; i < 8; ++i) {
        half8_t wv = wl8[i * 64 + lane];               // contiguous b128
        const half2_t* w2 = (const half2_t*)&wv;
#pragma unroll
        for (int r = 0; r < 4; ++r) {
            half8_t xv = ((const half8_t*)&xs[wid * 4 + r][0])[i];  // broadcast b128
            const half2_t* x2 = (const half2_t*)&xv;
            a0[r] = FDOT2(x2[0], w2[0], a0[r]);
            a1[r] = FDOT2(x2[1], w2[1], a1[r]);
            a0[r] = FDOT2(x2[2], w2[2], a0[r]);
            a1[r] = FDOT2(x2[3], w2[3], a1[r]);
        }
    }

#pragma unroll
    for (int r = 0; r < 4; ++r) {
        float acc = a0[r] + a1[r];
        float vm = (lane < 40) ? acc : -INFINITY;
        float m = vm;
#pragma unroll
        for (int o = 32; o; o >>= 1) m = fmaxf(m, __shfl_xor(m, o));
        float e = (lane < 40) ? expf(vm - m) : 0.f;
        float s = e;
#pragma unroll
        for (int o = 32; o; o >>= 1) s += __shfl_xor(s, o);
        float ls = logf(s);
        const int grow = row0 + wid * 4 + r;
        if (grow < n && lane < 40) out[(size_t)grow * 40 + lane] = vm - m - ls;
    }
}

extern "C" void kernel_launch(void* const* d_in, const int* in_sizes, int n_in,
                              void* d_out, int out_size, void* d_ws, size_t ws_size,
                              hipStream_t stream) {
    const float* x   = (const float*)d_in[0];
    const int*   ei  = (const int*)d_in[1];
    const float* W1  = (const float*)d_in[2];
    const float* b1  = (const float*)d_in[3];
    const float* W2  = (const float*)d_in[4];
    const float* b2  = (const float*)d_in[5];
    const float* Wp1 = (const float*)d_in[6];
    const float* bp1 = (const float*)d_in[7];
    const float* Wp2 = (const float*)d_in[8];
    const float* bp2 = (const float*)d_in[9];
    float* out = (float*)d_out;

    const int N = in_sizes[0] / 64;
    const int E = in_sizes[1] / 2;
    const int* src = ei;
    const int* dst = ei + E;

    // Workspace
    char*  wsb = (char*)d_ws;
    size_t off = 0;
    auto alloc = [&](size_t bytes) { void* p = wsb + off; off += (bytes + 511) & ~(size_t)511; return p; };
    int*            cnt = (int*)alloc((size_t)N * 4);
    unsigned short* col = (unsigned short*)alloc((size_t)N * CAP * 2);
    half_t*         Wt  = (half_t*)alloc((size_t)3 * 4096 * 2);   // chunk-major W2,Wp1,Wp2
    half_t*         Ha  = (half_t*)alloc((size_t)N * 64 * 2);     // H1, later H3
    half_t*         Hb  = (half_t*)alloc((size_t)N * 64 * 2);     // H2
    (void)ws_size; (void)n_in; (void)out_size;

    const int nb16 = (N + 15) / 16;
    const int nb8  = (N + 7) / 8;

    hipMemsetAsync(cnt, 0, (size_t)N * 4, stream);
    build_h1<<<EDGE_BLOCKS + nb16, 256, 0, stream>>>(src, dst, x, W1, b1, W2, Wp1, Wp2,
                                                     Wt, cnt, col, Ha, E, N);             // CSR + H1
    fused_gather_gemm<<<nb8, 512, 0, stream>>>(Ha, cnt, col, Wt + 0 * 4096, b2, Hb, N, nb8);   // H2
    fused_gather_gemm<<<nb8, 512, 0, stream>>>(Hb, cnt, col, Wt + 1 * 4096, bp1, Ha, N, nb8);  // H3
    gemm40_softmax<<<nb16, 256, 0, stream>>>(Ha, Wt + 2 * 4096, bp2, out, N, nb16);            // out
}

// Round 23
// 125.323 us; speedup vs baseline: 1.0255x; 1.0255x over previous
//
#include <hip/hip_runtime.h>
#include <cmath>

// GraphSAGE forward for MI355X (gfx950).
// R23: R21 base (best, 128.0us) + cnt padded to one counter per 128B line
//      (stride-32 int): 800k atomics previously hit ~200 L2 lines per XCD
//      (32 counters/line) -> suspected line-granular atomic serialization.
//      Padding gives 32x more distinct lines. All else identical to R21.

typedef _Float16 half_t;
typedef half_t half2_t __attribute__((ext_vector_type(2)));
typedef half_t half4_t __attribute__((ext_vector_type(4)));
typedef half_t half8_t __attribute__((ext_vector_type(8)));

#if defined(__has_builtin)
# if __has_builtin(__builtin_amdgcn_fdot2)
#  define FDOT2(a, b, c) __builtin_amdgcn_fdot2((a), (b), (c), false)
# endif
#endif
#ifndef FDOT2
# define FDOT2(a, b, c) fmaf((float)(a)[0], (float)(b)[0], fmaf((float)(a)[1], (float)(b)[1], (c)))
#endif

#define NXCD 8
#define CAP  64          // bin capacity == wave width
#define EDGE_BLOCKS 2048 // 256 blocks/group
#define CSTR 32          // cnt stride in ints: 1 counter per 128B line

// --- Fused: binned CSR build + wconv (edge blocks) || H1 GEMM (trailing blocks) ---
// Wt chunk-major: Wt[m*4096 + i*512 + c*8 + j] = Wsrc[(i*8+j)*KOUT + c].
__global__ __launch_bounds__(256) void build_h1(
    const int* __restrict__ src, const int* __restrict__ dst,
    const float* __restrict__ x, const float* __restrict__ W1,
    const float* __restrict__ b1,
    const float* __restrict__ W2, const float* __restrict__ Wp1,
    const float* __restrict__ Wp2,
    half_t* __restrict__ Wt, int* __restrict__ cnt,
    unsigned short* __restrict__ col, half_t* __restrict__ Hh,
    int E, int N)
{
    const int tid = threadIdx.x;

    if (blockIdx.x < EDGE_BLOCKS) {
        int gid = blockIdx.x * 256 + tid;
        if (gid < 3 * 4096) {       // wconv -> chunk-major fp16
            int which = gid >> 12, r = gid & 4095;
            int i = r >> 9, c = (r >> 3) & 63, j = r & 7;
            int k = i * 8 + j;
            float v;
            if      (which == 0) v = W2[k * 64 + c];
            else if (which == 1) v = Wp1[k * 64 + c];
            else                 v = (c < 40) ? Wp2[k * 40 + c] : 0.f;
            Wt[gid] = (half_t)v;
        }

        const int g     = blockIdx.x & (NXCD - 1);
        const int bpg   = blockIdx.x >> 3;
        const int nbpg  = EDGE_BLOCKS >> 3;
        const int chunk = (N + NXCD - 1) / NXCD;
        const int lo = g * chunk;
        const int hi = min(N, lo + chunk);
        const int4* src4 = (const int4*)src;
        const int4* dst4 = (const int4*)dst;
        const int quads = E >> 2;
        for (int q = bpg * 256 + tid; q < quads; q += nbpg * 256) {
            int4 s4 = src4[q];
            bool any = (s4.x >= lo && s4.x < hi) || (s4.y >= lo && s4.y < hi) ||
                       (s4.z >= lo && s4.z < hi) || (s4.w >= lo && s4.w < hi);
            if (!any) continue;
            int4 d4 = dst4[q];
            if (s4.x >= lo && s4.x < hi) {
                int pos = atomicAdd(&cnt[(size_t)s4.x * CSTR], 1);
                if (pos < CAP) col[(size_t)s4.x * CAP + pos] = (unsigned short)d4.x;
            }
            if (s4.y >= lo && s4.y < hi) {
                int pos = atomicAdd(&cnt[(size_t)s4.y * CSTR], 1);
                if (pos < CAP) col[(size_t)s4.y * CAP + pos] = (unsigned short)d4.y;
            }
            if (s4.z >= lo && s4.z < hi) {
                int pos = atomicAdd(&cnt[(size_t)s4.z * CSTR], 1);
                if (pos < CAP) col[(size_t)s4.z * CAP + pos] = (unsigned short)d4.z;
            }
            if (s4.w >= lo && s4.w < hi) {
                int pos = atomicAdd(&cnt[(size_t)s4.w * CSTR], 1);
                if (pos < CAP) col[(size_t)s4.w * CAP + pos] = (unsigned short)d4.w;
            }
        }
        if (blockIdx.x == 0 && tid < (E & 3)) {
            int e = (E & ~3) + tid;
            int s = src[e];
            int pos = atomicAdd(&cnt[(size_t)s * CSTR], 1);
            if (pos < CAP) col[(size_t)s * CAP + pos] = (unsigned short)dst[e];
        }
    } else {
        // H1 GEMM: 16 rows/block, chunked W1 (low VGPR), raw fp32 W1 reads.
        __shared__ half_t xs[16][64];
        const int lane = tid & 63;
        const int wid  = tid >> 6;
        const int row0 = (blockIdx.x - EDGE_BLOCKS) * 16;

        for (int i = tid; i < 16 * 64; i += 256) {
            int rr = row0 + (i >> 6);
            float v = (rr < N) ? x[(size_t)row0 * 64 + i] : 0.f;
            xs[i >> 6][i & 63] = (half_t)v;
        }
        const float bias = b1[lane];
        __syncthreads();

        float acc[4] = {bias, bias, bias, bias};
#pragma unroll 1
        for (int c = 0; c < 4; ++c) {
            half2_t wr[8];
#pragma unroll
            for (int j = 0; j < 8; ++j) {
                float a0 = W1[(c * 16 + 2 * j + 0) * 64 + lane];
                float a1 = W1[(c * 16 + 2 * j + 1) * 64 + lane];
                half2_t h; h[0] = (half_t)a0; h[1] = (half_t)a1;
                wr[j] = h;
            }
#pragma unroll
            for (int r = 0; r < 4; ++r) {
                const half2_t* xp = (const half2_t*)&xs[wid * 4 + r][c * 16];
#pragma unroll
                for (int j = 0; j < 8; ++j) acc[r] = FDOT2(xp[j], wr[j], acc[r]);
            }
        }
#pragma unroll
        for (int r = 0; r < 4; ++r) {
            int grow = row0 + wid * 4 + r;
            if (grow < N) Hh[(size_t)grow * 64 + lane] = (half_t)acc[r];
        }
    }
}

// Half4 gather with pre-scaled byte offsets.
__device__ __forceinline__ void gather_node(const char* __restrict__ Hbytes,
                                            const unsigned short* __restrict__ cbase,
                                            int deg, int grp, int suboff, float* f) {
    const int myo = ((int)cbase[threadIdx.x & 63]) << 7;   // row byte offset
    f[0] = f[1] = f[2] = f[3] = 0.f;
    const int full = deg & ~15;
    int e = 0;
    for (; e < full; e += 16) {
        half4_t hacc; hacc[0] = (half_t)0.f; hacc[1] = (half_t)0.f;
        hacc[2] = (half_t)0.f; hacc[3] = (half_t)0.f;
#pragma unroll
        for (int i = 0; i < 4; ++i) {
            int off = __shfl(myo, e + 4 * i + grp);
            hacc += *(const half4_t*)(Hbytes + off + suboff);
        }
        f[0] += (float)hacc[0]; f[1] += (float)hacc[1];
        f[2] += (float)hacc[2]; f[3] += (float)hacc[3];
    }
    if (e < deg) {                                         // exec-masked tail
        half4_t hacc; hacc[0] = (half_t)0.f; hacc[1] = (half_t)0.f;
        hacc[2] = (half_t)0.f; hacc[3] = (half_t)0.f;
#pragma unroll
        for (int i = 0; i < 4; ++i) {
            int idx = e + 4 * i + grp;
            int off = __shfl(myo, idx & 63);
            if (idx < deg) hacc += *(const half4_t*)(Hbytes + off + suboff);
        }
        f[0] += (float)hacc[0]; f[1] += (float)hacc[1];
        f[2] += (float)hacc[2]; f[3] += (float)hacc[3];
    }
#pragma unroll
    for (int k = 0; k < 4; ++k) {
        f[k] += __shfl_xor(f[k], 16);
        f[k] += __shfl_xor(f[k], 32);
    }
}

// Linear LDS copy of a chunk-major 4096-half W image (uint4, coalesced).
__device__ __forceinline__ void stage_w(const half_t* __restrict__ Wt,
                                        half_t* __restrict__ wlds, int tid, int nthr) {
    const uint4* ws = (const uint4*)Wt;
    uint4* wd = (uint4*)wlds;
    for (int i = tid; i < 512; i += nthr) wd[i] = ws[i];
}

// b128-clean dot: acc pair += xrow . W(col=lane); W chunk-major in LDS.
__device__ __forceinline__ void dot64_b128(const half_t* __restrict__ xrow,
                                           const half_t* __restrict__ wlds,
                                           int lane, float& a0, float& a1) {
    const half8_t* wl8 = (const half8_t*)wlds;     // [8][64] half8
    const half8_t* xp8 = (const half8_t*)xrow;
#pragma unroll
    for (int i = 0; i < 8; ++i) {
        half8_t wv = wl8[i * 64 + lane];           // contiguous b128
        half8_t xv = xp8[i];                       // broadcast b128
        const half2_t* w2 = (const half2_t*)&wv;
        const half2_t* x2 = (const half2_t*)&xv;
        a0 = FDOT2(x2[0], w2[0], a0);
        a1 = FDOT2(x2[1], w2[1], a1);
        a0 = FDOT2(x2[2], w2[2], a0);
        a1 = FDOT2(x2[3], w2[3], a1);
    }
}

// Fused: Y[node] = relu(mean_gather(H)[node]) @ W + b. 512 thr = 8 waves = 8 nodes.
__global__ __launch_bounds__(512) void fused_gather_gemm(
    const half_t* __restrict__ H, const int* __restrict__ cnt,
    const unsigned short* __restrict__ colb, const half_t* __restrict__ Wt,
    const float* __restrict__ b, half_t* __restrict__ Y, int N)
{
    __shared__ __align__(16) half_t wlds[4096];
    __shared__ __align__(16) half_t xrow[8][64];
    const int tid  = threadIdx.x;
    const int w    = tid >> 6;
    const int lane = tid & 63;
    const int grp  = lane >> 4;
    const int sub  = lane & 15;

    stage_w(Wt, wlds, tid, 512);
    __syncthreads();                                   // only barrier

    const int node = blockIdx.x * 8 + w;
    if (node >= N) return;

    const int deg = cnt[(size_t)node * CSTR];
    float f[4];
    gather_node((const char*)H, colb + (size_t)node * CAP, deg, grp, sub * 8, f);
    if (grp == 0) {                                    // lanes 0-15 write 8B each
        float inv = (deg > 0) ? 1.f / (float)deg : 0.f;
        half4_t o;
        o[0] = (half_t)fmaxf(f[0] * inv, 0.f);
        o[1] = (half_t)fmaxf(f[1] * inv, 0.f);
        o[2] = (half_t)fmaxf(f[2] * inv, 0.f);
        o[3] = (half_t)fmaxf(f[3] * inv, 0.f);
        ((half4_t*)xrow[w])[sub] = o;                  // wave-private
    }

    float a0 = b[lane], a1 = 0.f;
    dot64_b128(xrow[w], wlds, lane, a0, a1);
    Y[(size_t)node * 64 + lane] = (half_t)(a0 + a1);
}

// out[row] = log_softmax( H3[row] @ Wp2 + bp2 ). Dense 16 rows/block; b128 reads.
__global__ __launch_bounds__(256) void gemm40_softmax(const half_t* __restrict__ H3,
                                                      const half_t* __restrict__ Wt2,
                                                      const float* __restrict__ bp2,
                                                      float* __restrict__ out, int n) {
    __shared__ __align__(16) half_t xs[16][64];
    __shared__ __align__(16) half_t wlds[4096];
    const int tid  = threadIdx.x;
    const int lane = tid & 63;
    const int wid  = tid >> 6;
    const int row0 = blockIdx.x * 16;

    stage_w(Wt2, wlds, tid, 256);
    {
        const half2_t* X2 = (const half2_t*)H3;
        half2_t z; z[0] = (half_t)0.f; z[1] = (half_t)0.f;
        for (int i = tid; i < 16 * 32; i += 256) {
            int rr = row0 + (i >> 5);
            ((half2_t*)xs)[i] = (rr < n) ? X2[(size_t)row0 * 32 + i] : z;
        }
    }
    const float bias2 = (lane < 40) ? bp2[lane] : 0.f;
    __syncthreads();

    float a0[4] = {bias2, bias2, bias2, bias2};
    float a1[4] = {0.f, 0.f, 0.f, 0.f};
    const half8_t* wl8 = (const half8_t*)wlds;
#pragma unroll
    for (int i = 0; i < 8; ++i) {
        half8_t wv = wl8[i * 64 + lane];               // contiguous b128
        const half2_t* w2 = (const half2_t*)&wv;
#pragma unroll
        for (int r = 0; r < 4; ++r) {
            half8_t xv = ((const half8_t*)&xs[wid * 4 + r][0])[i];  // broadcast b128
            const half2_t* x2 = (const half2_t*)&xv;
            a0[r] = FDOT2(x2[0], w2[0], a0[r]);
            a1[r] = FDOT2(x2[1], w2[1], a1[r]);
            a0[r] = FDOT2(x2[2], w2[2], a0[r]);
            a1[r] = FDOT2(x2[3], w2[3], a1[r]);
        }
    }

#pragma unroll
    for (int r = 0; r < 4; ++r) {
        float acc = a0[r] + a1[r];
        float vm = (lane < 40) ? acc : -INFINITY;
        float m = vm;
#pragma unroll
        for (int o = 32; o; o >>= 1) m = fmaxf(m, __shfl_xor(m, o));
        float e = (lane < 40) ? expf(vm - m) : 0.f;
        float s = e;
#pragma unroll
        for (int o = 32; o; o >>= 1) s += __shfl_xor(s, o);
        float ls = logf(s);
        const int grow = row0 + wid * 4 + r;
        if (grow < n && lane < 40) out[(size_t)grow * 40 + lane] = vm - m - ls;
    }
}

extern "C" void kernel_launch(void* const* d_in, const int* in_sizes, int n_in,
                              void* d_out, int out_size, void* d_ws, size_t ws_size,
                              hipStream_t stream) {
    const float* x   = (const float*)d_in[0];
    const int*   ei  = (const int*)d_in[1];
    const float* W1  = (const float*)d_in[2];
    const float* b1  = (const float*)d_in[3];
    const float* W2  = (const float*)d_in[4];
    const float* b2  = (const float*)d_in[5];
    const float* Wp1 = (const float*)d_in[6];
    const float* bp1 = (const float*)d_in[7];
    const float* Wp2 = (const float*)d_in[8];
    const float* bp2 = (const float*)d_in[9];
    float* out = (float*)d_out;

    const int N = in_sizes[0] / 64;
    const int E = in_sizes[1] / 2;
    const int* src = ei;
    const int* dst = ei + E;

    // Workspace
    char*  wsb = (char*)d_ws;
    size_t off = 0;
    auto alloc = [&](size_t bytes) { void* p = wsb + off; off += (bytes + 511) & ~(size_t)511; return p; };
    int*            cnt = (int*)alloc((size_t)N * CSTR * 4);      // 1 counter / 128B line
    unsigned short* col = (unsigned short*)alloc((size_t)N * CAP * 2);
    half_t*         Wt  = (half_t*)alloc((size_t)3 * 4096 * 2);   // chunk-major W2,Wp1,Wp2
    half_t*         Ha  = (half_t*)alloc((size_t)N * 64 * 2);     // H1, later H3
    half_t*         Hb  = (half_t*)alloc((size_t)N * 64 * 2);     // H2
    (void)ws_size; (void)n_in; (void)out_size;

    const int nb16 = (N + 15) / 16;
    const int nb8  = (N + 7) / 8;

    hipMemsetAsync(cnt, 0, (size_t)N * CSTR * 4, stream);
    build_h1<<<EDGE_BLOCKS + nb16, 256, 0, stream>>>(src, dst, x, W1, b1, W2, Wp1, Wp2,
                                                     Wt, cnt, col, Ha, E, N);             // CSR + H1
    fused_gather_gemm<<<nb8, 512, 0, stream>>>(Ha, cnt, col, Wt + 0 * 4096, b2, Hb, N);   // H2
    fused_gather_gemm<<<nb8, 512, 0, stream>>>(Hb, cnt, col, Wt + 1 * 4096, bp1, Ha, N);  // H3
    gemm40_softmax<<<nb16, 256, 0, stream>>>(Ha, Wt + 2 * 4096, bp2, out, N);             // out
}